// Round 1
// 634.231 us; speedup vs baseline: 1.4758x; 1.4758x over previous
//
#include <hip/hip_runtime.h>

// ============================================================================
// Fully-fused 3-layer Elman RNN, *** FP32 in/out ***, MFMA 16x16x32 bf16 via
// Ootomo 3-term double-bf16 products (ah*bh + ah*bl + al*bh, err ~2^-18).
//   B=8192, T=64, dims: 84 -> 128 -> 128 -> 84
// R4 change (latency attack): counters showed 1 wave/SIMD (Occupancy 11.9%,
// MfmaUtil 15.8%, 28k cycles/timestep vs ~1.3k of MFMA issue) -> pure
// latency-bound. Restructure 256thr/4waves(2 n-tiles each) ->
// 512thr/8waves(1 n-tile each):
//   - per-wave weight frags halve: 22 fragp = 176 VGPRs -> fits the 256-VGPR
//     cap of __launch_bounds__(512,2) => 2 waves/SIMD co-resident (same LDS,
//     still 1 block/CU, grid still 256 = 1 block/CU).
//   - L2 has only 6 live n-tiles (84 cols); the 2 dead tiles (cols 96..127)
//     are mapped to waves 3,7 (both SIMD 3) so SIMDs 0-2 keep dual-wave
//     overlap during L2. Dead waves skip L2 (no barrier after L2 -> safe).
//   - x_{t+1} staging split T14-style: global loads issued at timestep top
//     (hide under L0), convert+ds_write after barrier 1 (placement as before,
//     so the R1-R3 xbuf ping-pong hazard audit is unchanged).
// Barrier/parity structure is IDENTICAL to R3 (2 __syncthreads per timestep,
// audited); only wave->tile ownership and thread counts changed.
// ============================================================================

typedef __bf16 bf16x8 __attribute__((ext_vector_type(8)));
typedef float  f32x4  __attribute__((ext_vector_type(4)));
typedef unsigned short u16;
typedef unsigned int   u32;
typedef u16 u16x8 __attribute__((ext_vector_type(8)));

#define MFMA16(a, b, c) __builtin_amdgcn_mfma_f32_16x16x32_bf16((a), (b), (c), 0, 0, 0)

__device__ __forceinline__ float bf2f(u16 v) {
    return __builtin_bit_cast(float, (u32)v << 16);
}
// float -> bf16 round-to-nearest-even (finite inputs only)
__device__ __forceinline__ u16 f2bf(float f) {
    u32 u = __builtin_bit_cast(u32, f);
    u = u + 0x7fffu + ((u >> 16) & 1u);
    return (u16)(u >> 16);
}
__device__ __forceinline__ float tanh_fast(float x) {
    float xc = fminf(fmaxf(x, -12.f), 12.f);           // avoid inf/inf
    float e  = __expf(2.f * xc);
    return (e - 1.f) * __builtin_amdgcn_rcpf(e + 1.f); // ~1e-7 rel err
}
__device__ __forceinline__ f32x4 splat4(float v) {
    f32x4 r; r[0] = v; r[1] = v; r[2] = v; r[3] = v; return r;
}
__device__ __forceinline__ bf16x8 ld_lds8(const u16* p) {
    return __builtin_bit_cast(bf16x8, *(const u16x8*)p);
}
// split fp32 into hi+lo bf16 (v - hi exact in fp32; residual ~2^-18 * |v|)
__device__ __forceinline__ void store_hl(u16* ph, u16* pl, float v) {
    u16 hi = f2bf(v);
    *ph = hi;
    *pl = f2bf(v - bf2f(hi));
}

struct fragp { bf16x8 h, l; };   // hi/lo weight fragment pair

// B-frag pair for C = A @ W^T, W fp32 row-major [Hr][Kr]; lane col n holds
// W[n][kbase..kbase+8) split hi/lo. Zero-pads OOB rows/cols.
__device__ __forceinline__ fragp load_wfrag_hl(const float* W, int Hr, int Kr,
                                               int n, int kbase) {
    u16x8 uh = {0,0,0,0,0,0,0,0}, ul = {0,0,0,0,0,0,0,0};
    if (n < Hr) {
#pragma unroll
        for (int j = 0; j < 8; j++) {
            int k = kbase + j;
            if (k < Kr) {
                float w = W[n * Kr + k];
                u16 hi = f2bf(w);
                uh[j] = hi;
                ul[j] = f2bf(w - bf2f(hi));
            }
        }
    }
    fragp r;
    r.h = __builtin_bit_cast(bf16x8, uh);
    r.l = __builtin_bit_cast(bf16x8, ul);
    return r;
}

// 3-term double-bf16 product accumulate: c += (ah+al) * (bh+bl) - O(2^-18)
__device__ __forceinline__ f32x4 mm3(bf16x8 ah, bf16x8 al, const fragp& b, f32x4 c) {
    c = MFMA16(ah, b.h, c);
    c = MFMA16(ah, b.l, c);
    c = MFMA16(al, b.h, c);
    return c;
}

__global__ __launch_bounds__(512, 2)  // 8 waves, 2/SIMD: 256-VGPR cap, 176 used by weights
void rnn_fused(const float* __restrict__ x,
               const float* __restrict__ wih0, const float* __restrict__ whh0,
               const float* __restrict__ bih0, const float* __restrict__ bhh0,
               const float* __restrict__ wih1, const float* __restrict__ whh1,
               const float* __restrict__ bih1, const float* __restrict__ bhh1,
               const float* __restrict__ wih2, const float* __restrict__ whh2,
               const float* __restrict__ bih2, const float* __restrict__ bhh2,
               float* __restrict__ out)
{
    // hi/lo planes, double-buffered by t parity. Row strides 136/104/96 els:
    // 16B-aligned rows for ds_read_b128; 2-way bank alias is free (m136).
    __shared__ __align__(16) u16 h0h[2][32][136], h0l[2][32][136];
    __shared__ __align__(16) u16 h1h[2][32][136], h1l[2][32][136];
    __shared__ __align__(16) u16 h2h[2][32][104], h2l[2][32][104];
    __shared__ __align__(16) u16 xbh[2][32][96],  xbl[2][32][96];   // x_t staging

    const int tid  = threadIdx.x;
    const int wv   = tid >> 6;        // wave 0..7
    const int lane = tid & 63;
    const int ln   = lane & 15;       // A-row / C-col index
    const int q    = lane >> 4;       // quad
    // wave -> n-tile map: {0,1,2}->+{0,1,2}, 3->6, {4,5,6}->{3,4,5}, 7->7.
    // Tiles 6,7 (cols 96..127) are L2-dead; they land on waves 3,7 = SIMD 3,
    // keeping SIMDs 0-2 at 2 active waves during L2.
    const int nt   = ((wv & 3) == 3) ? (6 + (wv >> 2)) : ((wv >> 2) * 3 + (wv & 3));
    const int nw   = nt * 16 + ln;    // owned output column (0..127)
    const int b0   = blockIdx.x * 32;
    const float* xg = x + (long)b0 * 5376;   // this block's 32 batch rows

    // h_{-1} = 0 (parity-0 planes)
    { u16* z = &h0h[0][0][0]; for (int i = tid; i < 32 * 136; i += 512) z[i] = 0; }
    { u16* z = &h0l[0][0][0]; for (int i = tid; i < 32 * 136; i += 512) z[i] = 0; }
    { u16* z = &h1h[0][0][0]; for (int i = tid; i < 32 * 136; i += 512) z[i] = 0; }
    { u16* z = &h1l[0][0][0]; for (int i = tid; i < 32 * 136; i += 512) z[i] = 0; }
    { u16* z = &h2h[0][0][0]; for (int i = tid; i < 32 * 104; i += 512) z[i] = 0; }
    { u16* z = &h2l[0][0][0]; for (int i = tid; i < 32 * 104; i += 512) z[i] = 0; }
    // x pad cols 84..95, both parities, both planes (written once)
    for (int i = tid; i < 32 * 12 * 2; i += 512) {
        int par = i / (32 * 12), rem = i - par * 32 * 12;
        int row = rem / 12, col = 84 + rem - row * 12;
        xbh[par][row][col] = 0; xbl[par][row][col] = 0;
    }
    // stage x_0 into parity 0
    for (int i = tid; i < 32 * 84; i += 512) {
        int row = i / 84, col = i - row * 84;
        float v = xg[(long)row * 5376 + col];
        u16 hi = f2bf(v);
        xbh[0][row][col] = hi;
        xbl[0][row][col] = f2bf(v - bf2f(hi));
    }

    // ---- register-resident hi/lo weight B-frags: 22 fragp = 176 VGPRs ----
    fragp fih0[3], fhh0[4], fih1[4], fhh1[4], fih2[4], fhh2[3];
#pragma unroll
    for (int c = 0; c < 3; c++) {
        fih0[c] = load_wfrag_hl(wih0, 128, 84, nw, c * 32 + q * 8);
        fhh2[c] = load_wfrag_hl(whh2,  84, 84, nw, c * 32 + q * 8);  // nw>=84 -> zeros
    }
#pragma unroll
    for (int c = 0; c < 4; c++) {
        fhh0[c] = load_wfrag_hl(whh0, 128, 128, nw, c * 32 + q * 8);
        fih1[c] = load_wfrag_hl(wih1, 128, 128, nw, c * 32 + q * 8);
        fhh1[c] = load_wfrag_hl(whh1, 128, 128, nw, c * 32 + q * 8);
        fih2[c] = load_wfrag_hl(wih2,  84, 128, nw, c * 32 + q * 8); // nw>=84 -> zeros
    }
    const float bias0w = bih0[nw] + bhh0[nw];                  // nw < 128 always
    const float bias1w = bih1[nw] + bhh1[nw];
    const float bias2w = (nw < 84) ? bih2[nw] + bhh2[nw] : 0.f;

    __syncthreads();

    f32x4 acc0, acc1;        // [m-tile 0/1] for this wave's single n-tile
    float xs[6];             // T14 issue-early staging regs (32*84/512 = 5.25)

    for (int t = 0; t < 64; ++t) {
        const int p = t & 1, pn = p ^ 1;

        // -- T14 issue-early: global loads for x_{t+1}; consumed after bar 1.
        if (t < 63) {
#pragma unroll
            for (int j = 0; j < 6; j++) {
                int i = tid + j * 512;
                if (i < 32 * 84) {
                    int row = i / 84, col = i - row * 84;
                    xs[j] = xg[(long)row * 5376 + (t + 1) * 84 + col];
                }
            }
        }

        // ================= layer 0 : 84 -> 128 =================
        acc0 = splat4(bias0w); acc1 = splat4(bias0w);
#pragma unroll
        for (int c = 0; c < 3; c++) {            // x-projection from staged x_t
            const int off = c * 32 + q * 8;
            bf16x8 a0h = ld_lds8(&xbh[p][ln][off]),      a0l = ld_lds8(&xbl[p][ln][off]);
            bf16x8 a1h = ld_lds8(&xbh[p][16 + ln][off]), a1l = ld_lds8(&xbl[p][16 + ln][off]);
            acc0 = mm3(a0h, a0l, fih0[c], acc0);
            acc1 = mm3(a1h, a1l, fih0[c], acc1);
        }
#pragma unroll
        for (int c = 0; c < 4; c++) {            // recurrence
            const int off = c * 32 + q * 8;
            bf16x8 a0h = ld_lds8(&h0h[p][ln][off]),      a0l = ld_lds8(&h0l[p][ln][off]);
            bf16x8 a1h = ld_lds8(&h0h[p][16 + ln][off]), a1l = ld_lds8(&h0l[p][16 + ln][off]);
            acc0 = mm3(a0h, a0l, fhh0[c], acc0);
            acc1 = mm3(a1h, a1l, fhh0[c], acc1);
        }
#pragma unroll
        for (int r = 0; r < 4; r++) {            // C/D: row = q*4+r, col = nw
            const int row = q * 4 + r;
            store_hl(&h0h[pn][row     ][nw], &h0l[pn][row     ][nw], tanh_fast(acc0[r]));
            store_hl(&h0h[pn][16 + row][nw], &h0l[pn][16 + row][nw], tanh_fast(acc1[r]));
        }
        __syncthreads();   // barrier 1: h0_t ready for L1

        // write-late half of x_{t+1} staging into xbuf[pn]
        // (read by L0 of t+1 after barrier 2 -> safe, same slot as R3)
        if (t < 63) {
#pragma unroll
            for (int j = 0; j < 6; j++) {
                int i = tid + j * 512;
                if (i < 32 * 84) {
                    int row = i / 84, col = i - row * 84;
                    u16 hi = f2bf(xs[j]);
                    xbh[pn][row][col] = hi;
                    xbl[pn][row][col] = f2bf(xs[j] - bf2f(hi));
                }
            }
        }

        // ================= layer 1 : 128 -> 128 =================
        acc0 = splat4(bias1w); acc1 = splat4(bias1w);
#pragma unroll
        for (int c = 0; c < 4; c++) {            // input proj from h0_t
            const int off = c * 32 + q * 8;
            bf16x8 a0h = ld_lds8(&h0h[pn][ln][off]),      a0l = ld_lds8(&h0l[pn][ln][off]);
            bf16x8 a1h = ld_lds8(&h0h[pn][16 + ln][off]), a1l = ld_lds8(&h0l[pn][16 + ln][off]);
            acc0 = mm3(a0h, a0l, fih1[c], acc0);
            acc1 = mm3(a1h, a1l, fih1[c], acc1);
        }
#pragma unroll
        for (int c = 0; c < 4; c++) {            // recurrence
            const int off = c * 32 + q * 8;
            bf16x8 a0h = ld_lds8(&h1h[p][ln][off]),      a0l = ld_lds8(&h1l[p][ln][off]);
            bf16x8 a1h = ld_lds8(&h1h[p][16 + ln][off]), a1l = ld_lds8(&h1l[p][16 + ln][off]);
            acc0 = mm3(a0h, a0l, fhh1[c], acc0);
            acc1 = mm3(a1h, a1l, fhh1[c], acc1);
        }
#pragma unroll
        for (int r = 0; r < 4; r++) {
            const int row = q * 4 + r;
            store_hl(&h1h[pn][row     ][nw], &h1l[pn][row     ][nw], tanh_fast(acc0[r]));
            store_hl(&h1h[pn][16 + row][nw], &h1l[pn][16 + row][nw], tanh_fast(acc1[r]));
        }
        __syncthreads();   // barrier 2: h1_t (and x_{t+1}) ready

        // ================= layer 2 : 128 -> 84 =================
        // Tiles 6,7 (waves 3,7) are all-padding: skip entirely. Safe: no
        // barrier after L2; their early entry into L0(t+1) only touches
        // xb[pn]/h0[pn] (ready at barrier 2) and writes h0[p] (last read
        // before barrier 1 of t). Same hazard set as R3's audit.
        if (nt < 6) {
            acc0 = splat4(bias2w); acc1 = splat4(bias2w);
#pragma unroll
            for (int c = 0; c < 4; c++) {        // input proj from h1_t
                const int off = c * 32 + q * 8;
                bf16x8 a0h = ld_lds8(&h1h[pn][ln][off]),      a0l = ld_lds8(&h1l[pn][ln][off]);
                bf16x8 a1h = ld_lds8(&h1h[pn][16 + ln][off]), a1l = ld_lds8(&h1l[pn][16 + ln][off]);
                acc0 = mm3(a0h, a0l, fih2[c], acc0);
                acc1 = mm3(a1h, a1l, fih2[c], acc1);
            }
#pragma unroll
            for (int c = 0; c < 3; c++) {        // recurrence (K=96, 84 zero-padded)
                const int off = c * 32 + q * 8;
                bf16x8 a0h = ld_lds8(&h2h[p][ln][off]),      a0l = ld_lds8(&h2l[p][ln][off]);
                bf16x8 a1h = ld_lds8(&h2h[p][16 + ln][off]), a1l = ld_lds8(&h2l[p][16 + ln][off]);
                acc0 = mm3(a0h, a0l, fhh2[c], acc0);
                acc1 = mm3(a1h, a1l, fhh2[c], acc1);
            }
            // epilogue: pad cols (84..95) compute to exactly 0 (zeroed W+bias)
#pragma unroll
            for (int r = 0; r < 4; r++) {
                const int row = q * 4 + r;
                float v0 = tanh_fast(acc0[r]);
                float v1 = tanh_fast(acc1[r]);
                store_hl(&h2h[pn][row     ][nw], &h2l[pn][row     ][nw], v0);
                store_hl(&h2h[pn][16 + row][nw], &h2l[pn][16 + row][nw], v1);
                if (nw < 84) {
                    out[(long)(b0 + row)      * 5376 + t * 84 + nw] = v0;
                    out[(long)(b0 + 16 + row) * 5376 + t * 84 + nw] = v1;
                }
            }
        }
        // no barrier here: next-step L0 reads h0[pn]/xbuf[pn] only; all
        // remaining ping-pong hazards separated by the next iteration's two
        // barriers (audit unchanged from R3).
    }
}

extern "C" void kernel_launch(void* const* d_in, const int* in_sizes, int n_in,
                              void* d_out, int out_size, void* d_ws, size_t ws_size,
                              hipStream_t stream) {
    (void)in_sizes; (void)n_in; (void)out_size; (void)d_ws; (void)ws_size;
    const float* x    = (const float*)d_in[0];
    const float* wih0 = (const float*)d_in[1];
    const float* whh0 = (const float*)d_in[2];
    const float* bih0 = (const float*)d_in[3];
    const float* bhh0 = (const float*)d_in[4];
    const float* wih1 = (const float*)d_in[5];
    const float* whh1 = (const float*)d_in[6];
    const float* bih1 = (const float*)d_in[7];
    const float* bhh1 = (const float*)d_in[8];
    const float* wih2 = (const float*)d_in[9];
    const float* whh2 = (const float*)d_in[10];
    const float* bih2 = (const float*)d_in[11];
    const float* bhh2 = (const float*)d_in[12];
    float* out = (float*)d_out;

    rnn_fused<<<dim3(8192 / 32), dim3(512), 0, stream>>>(
        x, wih0, whh0, bih0, bhh0, wih1, whh1, bih1, bhh1,
        wih2, whh2, bih2, bhh2, out);
}